// Round 1
// baseline (10622.047 us; speedup 1.0000x reference)
//
#include <hip/hip_runtime.h>
#include <cstddef>

// Problem constants
constexpr int Bc = 64;
constexpr int Sc = 200;
constexpr int Hc = 4;
constexpr int Dc = 256;
constexpr int HDc = 64;
constexpr int NPc = Bc * Sc;          // 12800 rows
constexpr int NPROJ = 15;

// proj indices
// 0 iq, 1 ik, 2 iv, 3 pq, 4 pk, 5 aq, 6 ak, 7 haq, 8 hak, 9 hav,
// 10 iqc, 11 ciq, 12 cqp, 13 cqp_a, 14 pqc

__constant__ int c_QI9[9] = {0,10,0,11,5,12,3,14,3};
__constant__ int c_KI9[9] = {1,6,4,1,6,4,1,6,4};
__constant__ int c_QI4[4] = {7,13,14,3};
__constant__ int c_KI4[4] = {8,4,8,4};

struct ProjArgs {
    const float* A[NPROJ];
    const float* W[NPROJ];
    const float* bias[NPROJ];
};

// ---------------------------------------------------------------------------
// Kernel 1: all 15 projections.  C[M,256] = A[M,256] @ W[256,256] + b
// block: 256 threads; tile: 32 rows x 256 cols; A tile staged in LDS.
// grid: (400, 15)
// ---------------------------------------------------------------------------
__global__ __launch_bounds__(256) void proj_kernel(ProjArgs args, float* __restrict__ proj_ws) {
    const int p  = blockIdx.y;
    const int m0 = blockIdx.x * 32;
    const float* __restrict__ A    = args.A[p];
    const float* __restrict__ W    = args.W[p];
    const float* __restrict__ bias = args.bias[p];
    float* __restrict__ out = proj_ws + (size_t)p * NPc * Dc;

    __shared__ float As[32][256];
    const int tid = threadIdx.x;

    for (int t = tid; t < 32 * 64; t += 256) {
        int r = t >> 6, k4 = t & 63;
        ((float4*)As[r])[k4] = ((const float4*)(A + (size_t)(m0 + r) * Dc))[k4];
    }
    __syncthreads();

    const int tx = tid & 63;   // col group: cols tx*4 .. tx*4+3
    const int ty = tid >> 6;   // 0..3 -> rows ty, ty+4, ..., ty+28

    float acc[8][4];
    #pragma unroll
    for (int i = 0; i < 8; i++)
        #pragma unroll
        for (int j = 0; j < 4; j++) acc[i][j] = 0.f;

    for (int k = 0; k < 256; k += 4) {
        float4 w0 = ((const float4*)(W + (size_t)(k    ) * Dc))[tx];
        float4 w1 = ((const float4*)(W + (size_t)(k + 1) * Dc))[tx];
        float4 w2 = ((const float4*)(W + (size_t)(k + 2) * Dc))[tx];
        float4 w3 = ((const float4*)(W + (size_t)(k + 3) * Dc))[tx];
        #pragma unroll
        for (int rr = 0; rr < 8; rr++) {
            int r = ty + rr * 4;
            float4 a4 = ((float4*)As[r])[k >> 2];
            acc[rr][0] += a4.x * w0.x + a4.y * w1.x + a4.z * w2.x + a4.w * w3.x;
            acc[rr][1] += a4.x * w0.y + a4.y * w1.y + a4.z * w2.y + a4.w * w3.y;
            acc[rr][2] += a4.x * w0.z + a4.y * w1.z + a4.z * w2.z + a4.w * w3.z;
            acc[rr][3] += a4.x * w0.w + a4.y * w1.w + a4.z * w2.w + a4.w * w3.w;
        }
    }

    float4 bv = ((const float4*)bias)[tx];
    #pragma unroll
    for (int rr = 0; rr < 8; rr++) {
        int r = ty + rr * 4;
        float4 o;
        o.x = acc[rr][0] + bv.x;
        o.y = acc[rr][1] + bv.y;
        o.z = acc[rr][2] + bv.z;
        o.w = acc[rr][3] + bv.w;
        ((float4*)(out + (size_t)(m0 + r) * Dc))[tx] = o;
    }
}

// ---------------------------------------------------------------------------
// Kernel 1b: transpose Wf1 (200x200) -> Wf1T (so gate dot products stream rows)
// ---------------------------------------------------------------------------
__global__ void transpose200(const float* __restrict__ in, float* __restrict__ out) {
    int idx = blockIdx.x * 256 + threadIdx.x;
    if (idx < Sc * Sc) {
        int i = idx / Sc, j = idx % Sc;
        out[(size_t)j * Sc + i] = in[(size_t)i * Sc + j];
    }
}

// ---------------------------------------------------------------------------
// Kernel 2: fused scores + gate + channel softmax + row softmax + PV
// One block = (b, h, 4 rows).  grid = 64*4*50 = 12800 blocks of 256 threads.
// ---------------------------------------------------------------------------
template <int CH>
__global__ __launch_bounds__(256) void fused_attn_kernel(
    const float* __restrict__ proj_ws,
    const float* __restrict__ fw,        // CH fusion weights
    const float* __restrict__ mask,      // (B,1,S,S)
    const float* __restrict__ Wf1T,      // (S,S) transposed: [j][i]
    const float* __restrict__ bf1,       // (S)
    const float* __restrict__ Wf2,       // (S)
    const float* __restrict__ bf2p,      // (1)
    float* __restrict__ ctx_out,         // (B,S,D) with head cols h*64..h*64+63
    int vproj)
{
    constexpr int R = 4;
    __shared__ float qs[CH][R][HDc];
    __shared__ float sc[CH][R][Sc];
    __shared__ float g[R][Sc];
    __shared__ float evals[CH * R];
    __shared__ float wch[CH * R];

    const int bid = blockIdx.x;
    const int rt = bid % (Sc / R);            // 0..49
    const int h  = (bid / (Sc / R)) & (Hc - 1);
    const int b  = bid / ((Sc / R) * Hc);
    const int r0 = rt * R;
    const int tid = threadIdx.x;

    const int* QI;
    const int* KI;
    if constexpr (CH == 9) { QI = c_QI9; KI = c_KI9; }
    else                   { QI = c_QI4; KI = c_KI4; }

    // ---- load Q rows for all channels (float4 granularity)
    for (int t = tid; t < CH * R * (HDc / 4); t += 256) {
        int c  = t / (R * 16);
        int r  = (t / 16) % R;
        int d4 = t % 16;
        const float* src = proj_ws + ((size_t)QI[c] * NPc + (size_t)(b * Sc + r0 + r)) * Dc + h * HDc;
        ((float4*)qs[c][r])[d4] = ((const float4*)src)[d4];
    }
    __syncthreads();

    // ---- scores: sc[c][r][j] = fw[c] * (q . k_j)
    for (int idx = tid; idx < CH * R * Sc; idx += 256) {
        int c   = idx / (R * Sc);
        int rem = idx % (R * Sc);
        int r   = rem / Sc;
        int j   = rem % Sc;
        const float4* k4 = (const float4*)(proj_ws + ((size_t)KI[c] * NPc + (size_t)(b * Sc + j)) * Dc + h * HDc);
        const float4* q4 = (const float4*)qs[c][r];
        float dot = 0.f;
        #pragma unroll
        for (int d = 0; d < 16; d++) {
            float4 kv = k4[d];
            float4 qv = q4[d];
            dot += qv.x * kv.x + qv.y * kv.y + qv.z * kv.z + qv.w * kv.w;
        }
        sc[c][r][j] = dot * fw[c];
    }
    __syncthreads();

    const int lane = tid & 63;
    const int wv   = tid >> 6;   // wave id 0..3
    const float bf2v = bf2p[0];

    // ---- gate: e[p] = sum_j relu( sc_row . Wf1[:,j] + bf1[j] ) * Wf2[j] + bf2
    for (int p = wv; p < CH * R; p += 4) {
        int c = p / R, r = p % R;
        float epart = 0.f;
        const float4* srow = (const float4*)sc[c][r];
        for (int jt = 0; jt < 4; jt++) {
            int j = jt * 64 + lane;
            if (j < Sc) {
                float tacc = bf1[j];
                const float4* wrow = (const float4*)(Wf1T + (size_t)j * Sc);
                #pragma unroll 10
                for (int i4 = 0; i4 < Sc / 4; i4++) {
                    float4 a = srow[i4];
                    float4 w = wrow[i4];
                    tacc += a.x * w.x + a.y * w.y + a.z * w.z + a.w * w.w;
                }
                epart += fmaxf(tacc, 0.f) * Wf2[j];
            }
        }
        #pragma unroll
        for (int off = 32; off >= 1; off >>= 1) epart += __shfl_xor(epart, off, 64);
        if (lane == 0) evals[p] = epart + bf2v;
    }
    __syncthreads();

    // ---- channel softmax per row
    if (tid < R) {
        int r = tid;
        float m = -1e30f;
        #pragma unroll
        for (int c = 0; c < CH; c++) m = fmaxf(m, evals[c * R + r]);
        float s = 0.f;
        #pragma unroll
        for (int c = 0; c < CH; c++) {
            float ex = __expf(evals[c * R + r] - m);
            wch[c * R + r] = ex;
            s += ex;
        }
        float inv = 1.f / s;
        #pragma unroll
        for (int c = 0; c < CH; c++) wch[c * R + r] *= inv;
    }
    __syncthreads();

    // ---- gated scores + scale + mask
    constexpr float scale = 0.125f;  // 1/sqrt(64)
    for (int idx = tid; idx < R * Sc; idx += 256) {
        int r = idx / Sc, j = idx % Sc;
        float v = 0.f;
        #pragma unroll
        for (int c = 0; c < CH; c++) v += wch[c * R + r] * sc[c][r][j];
        g[r][j] = v * scale + mask[((size_t)b * Sc + (r0 + r)) * Sc + j];
    }
    __syncthreads();

    // ---- row softmax (wave wv owns row wv)
    {
        int r = wv;
        float vals[4];
        float mpart = -1e30f;
        #pragma unroll
        for (int t4 = 0; t4 < 4; t4++) {
            int j = t4 * 64 + lane;
            vals[t4] = (j < Sc) ? g[r][j] : -1e30f;
            mpart = fmaxf(mpart, vals[t4]);
        }
        #pragma unroll
        for (int off = 32; off >= 1; off >>= 1) mpart = fmaxf(mpart, __shfl_xor(mpart, off, 64));
        float spart = 0.f;
        #pragma unroll
        for (int t4 = 0; t4 < 4; t4++) {
            int j = t4 * 64 + lane;
            if (j < Sc) {
                float ex = __expf(vals[t4] - mpart);
                g[r][j] = ex;
                spart += ex;
            }
        }
        #pragma unroll
        for (int off = 32; off >= 1; off >>= 1) spart += __shfl_xor(spart, off, 64);
        float inv = 1.f / spart;
        #pragma unroll
        for (int t4 = 0; t4 < 4; t4++) {
            int j = t4 * 64 + lane;
            if (j < Sc) g[r][j] *= inv;
        }
    }
    __syncthreads();

    // ---- PV: ctx[r][d] = sum_j p[r][j] * V[j][d]
    {
        int r = wv;
        int d = lane;
        const float* vbase = proj_ws + (size_t)vproj * NPc * Dc + (size_t)(b * Sc) * Dc + h * HDc + d;
        float acc = 0.f;
        for (int j = 0; j < Sc; j++) acc += g[r][j] * vbase[(size_t)j * Dc];
        ctx_out[((size_t)(b * Sc + r0 + r)) * Dc + h * HDc + d] = acc;
    }
}

// ---------------------------------------------------------------------------
// Kernel 3: out = LayerNorm( A @ W + bias + resid ) * gamma + beta
// block: 256 threads, 16 rows per block.  grid = 800
// ---------------------------------------------------------------------------
__global__ __launch_bounds__(256) void out_ln_kernel(
    const float* __restrict__ Actx,
    const float* __restrict__ W,
    const float* __restrict__ bias,
    const float* __restrict__ resid,
    const float* __restrict__ gamma,
    const float* __restrict__ beta,
    float* __restrict__ out)
{
    const int m0 = blockIdx.x * 16;
    const int tid = threadIdx.x;   // column

    __shared__ float As[16][256];
    __shared__ float ylds[16][256];

    for (int t = tid; t < 16 * 64; t += 256) {
        int r = t >> 6, k4 = t & 63;
        ((float4*)As[r])[k4] = ((const float4*)(Actx + (size_t)(m0 + r) * Dc))[k4];
    }
    __syncthreads();

    float acc[16];
    #pragma unroll
    for (int r = 0; r < 16; r++) acc[r] = 0.f;

    for (int k = 0; k < 256; k += 4) {
        float w0 = W[(size_t)(k    ) * Dc + tid];
        float w1 = W[(size_t)(k + 1) * Dc + tid];
        float w2 = W[(size_t)(k + 2) * Dc + tid];
        float w3 = W[(size_t)(k + 3) * Dc + tid];
        #pragma unroll
        for (int r = 0; r < 16; r++) {
            float4 a4 = ((float4*)As[r])[k >> 2];
            acc[r] += a4.x * w0 + a4.y * w1 + a4.z * w2 + a4.w * w3;
        }
    }

    const float bv = bias[tid];
    #pragma unroll
    for (int r = 0; r < 16; r++) {
        float y = acc[r] + bv + resid[(size_t)(m0 + r) * Dc + tid];
        ylds[r][tid] = y;
    }
    __syncthreads();

    const int lane = tid & 63;
    const int wv   = tid >> 6;
    for (int r = wv * 4; r < wv * 4 + 4; r++) {
        float v4[4];
        float s = 0.f, s2 = 0.f;
        #pragma unroll
        for (int t4 = 0; t4 < 4; t4++) {
            float v = ylds[r][t4 * 64 + lane];
            v4[t4] = v;
            s += v;
            s2 += v * v;
        }
        #pragma unroll
        for (int off = 32; off >= 1; off >>= 1) {
            s  += __shfl_xor(s, off, 64);
            s2 += __shfl_xor(s2, off, 64);
        }
        float m   = s * (1.f / 256.f);
        float var = s2 * (1.f / 256.f) - m * m;
        float rstd = rsqrtf(var + 1e-12f);
        #pragma unroll
        for (int t4 = 0; t4 < 4; t4++) {
            int ccol = t4 * 64 + lane;
            out[(size_t)(m0 + r) * Dc + ccol] = (v4[t4] - m) * rstd * gamma[ccol] + beta[ccol];
        }
    }
}

// ---------------------------------------------------------------------------
// Launcher
// ---------------------------------------------------------------------------
extern "C" void kernel_launch(void* const* d_in, const int* in_sizes, int n_in,
                              void* d_out, int out_size, void* d_ws, size_t ws_size,
                              hipStream_t stream) {
    const float* X    = (const float*)d_in[0];   // input_tensor (B,S,D)
    const float* AT   = (const float*)d_in[1];   // attribute_table -> (B,S,AD)
    const float* P    = (const float*)d_in[2];   // position_embedding
    const float* HA   = (const float*)d_in[3];   // hidden_state_attr -> (B,S,AD)
    const float* mask = (const float*)d_in[4];   // (B,1,S,S)
    const float* fw   = (const float*)d_in[5];   // (9)
    const float* fwc  = (const float*)d_in[6];   // (4)

    // params start at 7
    const float* Wq   = (const float*)d_in[7];
    const float* bq   = (const float*)d_in[8];
    const float* Wk   = (const float*)d_in[9];
    const float* bk   = (const float*)d_in[10];
    const float* Wv   = (const float*)d_in[11];
    const float* bv   = (const float*)d_in[12];
    const float* Wqp  = (const float*)d_in[13];
    const float* bqp  = (const float*)d_in[14];
    const float* Wkp  = (const float*)d_in[15];
    const float* bkp  = (const float*)d_in[16];
    const float* Waq  = (const float*)d_in[17];
    const float* baq  = (const float*)d_in[18];
    const float* Wak  = (const float*)d_in[19];
    const float* bak  = (const float*)d_in[20];
    const float* Wav  = (const float*)d_in[21];
    const float* bav  = (const float*)d_in[22];
    const float* Wqic = (const float*)d_in[23];
    const float* bqic = (const float*)d_in[24];
    const float* Wqci = (const float*)d_in[25];
    const float* bqci = (const float*)d_in[26];
    const float* Wqpc = (const float*)d_in[27];
    const float* bqpc = (const float*)d_in[28];
    const float* Wqcp = (const float*)d_in[29];
    const float* bqcp = (const float*)d_in[30];
    const float* Wf1  = (const float*)d_in[31];
    const float* bf1  = (const float*)d_in[32];
    const float* Wf2  = (const float*)d_in[33];
    const float* bf2  = (const float*)d_in[34];
    const float* Wd   = (const float*)d_in[35];
    const float* bd   = (const float*)d_in[36];
    const float* ln_g = (const float*)d_in[37];
    const float* ln_b = (const float*)d_in[38];
    const float* Wda  = (const float*)d_in[39];
    const float* bda  = (const float*)d_in[40];
    const float* lna_g= (const float*)d_in[41];
    const float* lna_b= (const float*)d_in[42];

    float* wsf = (float*)d_ws;
    float* proj_ws = wsf;                                    // 15 * 12800 * 256
    size_t off = (size_t)NPROJ * NPc * Dc;
    float* Wf1T = wsf + off;  off += (size_t)Sc * Sc;        // 40000
    float* ctx  = wsf + off;  off += (size_t)NPc * Dc;       // 3.27M
    float* ctxc = wsf + off;  off += (size_t)NPc * Dc;

    ProjArgs pa;
    const float* Amat[NPROJ] = {X, X, X, P, P, AT, AT, HA, HA, HA, X, AT, AT, HA, P};
    const float* Wmat[NPROJ] = {Wq, Wk, Wv, Wqp, Wkp, Waq, Wak, Waq, Wak, Wav, Wqic, Wqci, Wqcp, Wqcp, Wqpc};
    const float* bmat[NPROJ] = {bq, bk, bv, bqp, bkp, baq, bak, baq, bak, bav, bqic, bqci, bqcp, bqcp, bqpc};
    for (int i = 0; i < NPROJ; i++) { pa.A[i] = Amat[i]; pa.W[i] = Wmat[i]; pa.bias[i] = bmat[i]; }

    // 1. projections
    proj_kernel<<<dim3(NPc / 32, NPROJ), 256, 0, stream>>>(pa, proj_ws);

    // 1b. transpose Wf1
    transpose200<<<(Sc * Sc + 255) / 256, 256, 0, stream>>>(Wf1, Wf1T);

    // 2. fused attention (9-channel -> ctx with V=iv(2); 4-channel -> ctxc with V=hav(9))
    fused_attn_kernel<9><<<Bc * Hc * (Sc / 4), 256, 0, stream>>>(
        proj_ws, fw, mask, Wf1T, bf1, Wf2, bf2, ctx, 2);
    fused_attn_kernel<4><<<Bc * Hc * (Sc / 4), 256, 0, stream>>>(
        proj_ws, fwc, mask, Wf1T, bf1, Wf2, bf2, ctxc, 9);

    // 3. output projections + residual + LayerNorm
    float* out0 = (float*)d_out;
    float* out1 = out0 + (size_t)NPc * Dc;
    out_ln_kernel<<<NPc / 16, 256, 0, stream>>>(ctx,  Wd,  bd,  X,  ln_g,  ln_b,  out0);
    out_ln_kernel<<<NPc / 16, 256, 0, stream>>>(ctxc, Wda, bda, HA, lna_g, lna_b, out1);
}

// Round 2
// 3344.636 us; speedup vs baseline: 3.1758x; 3.1758x over previous
//
#include <hip/hip_runtime.h>
#include <cstddef>

// Problem constants
constexpr int Bc = 64;
constexpr int Sc = 200;
constexpr int Hc = 4;
constexpr int Dc = 256;
constexpr int HDc = 64;
constexpr int NPc = Bc * Sc;          // 12800 rows
constexpr int NPROJ = 15;
constexpr float SCALE = 0.125f;       // 1/sqrt(64)

// proj indices
// 0 iq, 1 ik, 2 iv, 3 pq, 4 pk, 5 aq, 6 ak, 7 haq, 8 hak, 9 hav,
// 10 iqc, 11 ciq, 12 cqp, 13 cqp_a, 14 pqc

// per-channel Q projection index
__constant__ int c_QI9[9] = {0,10,0,11,5,12,3,14,3};
__constant__ int c_QI4[4] = {7,13,14,3};
// K-groups: channels grouped by shared K panel
__constant__ int c_KP9[3]  = {1,6,4};            // K proj per group
__constant__ int c_CHG9[9] = {0,3,6, 1,4,7, 2,5,8};  // [g*3+k] -> channel
__constant__ int c_KP4[2]  = {8,4};
__constant__ int c_CHG4[4] = {0,2, 1,3};

struct ProjArgs {
    const float* A[NPROJ];
    const float* W[NPROJ];
    const float* bias[NPROJ];
};

// ---------------------------------------------------------------------------
// Kernel 1: all 15 projections.  C[M,256] = A[M,256] @ W[256,256] + b
// ---------------------------------------------------------------------------
__global__ __launch_bounds__(256) void proj_kernel(ProjArgs args, float* __restrict__ proj_ws) {
    const int p  = blockIdx.y;
    const int m0 = blockIdx.x * 32;
    const float* __restrict__ A    = args.A[p];
    const float* __restrict__ W    = args.W[p];
    const float* __restrict__ bias = args.bias[p];
    float* __restrict__ out = proj_ws + (size_t)p * NPc * Dc;

    __shared__ float As[32][256];
    const int tid = threadIdx.x;

    for (int t = tid; t < 32 * 64; t += 256) {
        int r = t >> 6, k4 = t & 63;
        ((float4*)As[r])[k4] = ((const float4*)(A + (size_t)(m0 + r) * Dc))[k4];
    }
    __syncthreads();

    const int tx = tid & 63;
    const int ty = tid >> 6;

    float acc[8][4];
    #pragma unroll
    for (int i = 0; i < 8; i++)
        #pragma unroll
        for (int j = 0; j < 4; j++) acc[i][j] = 0.f;

    for (int k = 0; k < 256; k += 4) {
        float4 w0 = ((const float4*)(W + (size_t)(k    ) * Dc))[tx];
        float4 w1 = ((const float4*)(W + (size_t)(k + 1) * Dc))[tx];
        float4 w2 = ((const float4*)(W + (size_t)(k + 2) * Dc))[tx];
        float4 w3 = ((const float4*)(W + (size_t)(k + 3) * Dc))[tx];
        #pragma unroll
        for (int rr = 0; rr < 8; rr++) {
            int r = ty + rr * 4;
            float4 a4 = ((float4*)As[r])[k >> 2];
            acc[rr][0] += a4.x * w0.x + a4.y * w1.x + a4.z * w2.x + a4.w * w3.x;
            acc[rr][1] += a4.x * w0.y + a4.y * w1.y + a4.z * w2.y + a4.w * w3.y;
            acc[rr][2] += a4.x * w0.z + a4.y * w1.z + a4.z * w2.z + a4.w * w3.z;
            acc[rr][3] += a4.x * w0.w + a4.y * w1.w + a4.z * w2.w + a4.w * w3.w;
        }
    }

    float4 bv = ((const float4*)bias)[tx];
    #pragma unroll
    for (int rr = 0; rr < 8; rr++) {
        int r = ty + rr * 4;
        float4 o;
        o.x = acc[rr][0] + bv.x;
        o.y = acc[rr][1] + bv.y;
        o.z = acc[rr][2] + bv.z;
        o.w = acc[rr][3] + bv.w;
        ((float4*)(out + (size_t)(m0 + r) * Dc))[tx] = o;
    }
}

// ---------------------------------------------------------------------------
// Kernel 2 (v2): fused scores + gate GEMM + channel softmax + row softmax + PV
// One block = (b, h, 4 rows).  grid = 12800 blocks of 256 threads.
// ---------------------------------------------------------------------------
template <int CH>
__global__ __launch_bounds__(256) void fused2(
    const float* __restrict__ proj_ws,
    const float* __restrict__ fw,
    const float* __restrict__ mask,
    const float* __restrict__ Wf1,    // (S,S) natural row-major [i][j]
    const float* __restrict__ bf1,
    const float* __restrict__ Wf2,    // (S)
    const float* __restrict__ bf2p,
    float* __restrict__ ctx_out,
    int vproj)
{
    constexpr int R   = 4;
    constexpr int M   = CH * R;            // 36 or 16
    constexpr int MP  = M + 4;             // 40 or 20 (b128-aligned row stride)
    constexpr int NG  = (CH == 9) ? 3 : 2; // K-groups
    constexpr int CPG = (CH == 9) ? 3 : 2; // channels per group
    constexpr int JQn = (CH == 9) ? 25 : 50;  // j-quad threads in gate
    constexpr int RW  = JQn + 1;
    constexpr int NQ  = (CH == 9) ? 2 : 1;    // j-quads per gate thread

    __shared__ float bufA[128 * 68];  // Ks staging  |  gate: Ws[16][200] + red
    __shared__ float bufB[M * 68];    // qs (fw folded)  |  later: gbuf[4][200]
    __shared__ float scT[200 * MP];   // transposed gated scores scT[j][m]
    __shared__ float evals[M];
    __shared__ float wch[M];

    const int tid = threadIdx.x;
    const int bid = blockIdx.x;
    const int rt  = bid % (Sc / R);
    const int h   = (bid / (Sc / R)) & (Hc - 1);
    const int b   = bid / ((Sc / R) * Hc);
    const int r0  = rt * R;

    const int tx = tid & 63;
    const int ty = tid >> 6;

    // ---- stage q rows (all channels x 4 rows), fw folded in
    {
        const int* QI = (CH == 9) ? c_QI9 : c_QI4;
        for (int t = tid; t < M * 16; t += 256) {
            int m = t >> 4, q4 = t & 15;
            int c = m >> 2, r = m & 3;
            const float4 v = *(const float4*)(proj_ws +
                ((size_t)QI[c] * NPc + (size_t)(b * Sc + r0 + r)) * Dc + h * HDc + q4 * 4);
            float f = fw[c];
            *(float4*)(bufB + m * 68 + q4 * 4) = make_float4(v.x*f, v.y*f, v.z*f, v.w*f);
        }
    }
    __syncthreads();

    // ---- scores: for each K-group, stage K tile, GEMM into scT[j][m]
    {
        const int* KP  = (CH == 9) ? c_KP9  : c_KP4;
        const int* CHG = (CH == 9) ? c_CHG9 : c_CHG4;
        for (int g = 0; g < NG; ++g) {
            const float* Kbase = proj_ws + (size_t)KP[g] * NPc * Dc + (size_t)(b * Sc) * Dc + h * HDc;
            int mrow[CPG];
            #pragma unroll
            for (int k = 0; k < CPG; ++k) mrow[k] = CHG[g * CPG + k] * 4 + ty;

            // half A: j = 0..127 (thread tx owns j=tx and j=tx+64)
            for (int t = tid; t < 128 * 16; t += 256) {
                int r = t >> 4, q4 = t & 15;
                *(float4*)(bufA + r * 68 + q4 * 4) =
                    *(const float4*)(Kbase + (size_t)r * Dc + q4 * 4);
            }
            __syncthreads();
            {
                float acc0[CPG], acc1[CPG];
                #pragma unroll
                for (int k = 0; k < CPG; ++k) { acc0[k] = 0.f; acc1[k] = 0.f; }
                #pragma unroll
                for (int d0 = 0; d0 < 16; ++d0) {
                    float4 k0 = *(const float4*)(bufA + tx * 68 + d0 * 4);
                    float4 k1 = *(const float4*)(bufA + (tx + 64) * 68 + d0 * 4);
                    #pragma unroll
                    for (int k = 0; k < CPG; ++k) {
                        float4 q = *(const float4*)(bufB + mrow[k] * 68 + d0 * 4);
                        acc0[k] += q.x*k0.x + q.y*k0.y + q.z*k0.z + q.w*k0.w;
                        acc1[k] += q.x*k1.x + q.y*k1.y + q.z*k1.z + q.w*k1.w;
                    }
                }
                #pragma unroll
                for (int k = 0; k < CPG; ++k) {
                    scT[(size_t)tx * MP + mrow[k]]        = acc0[k];
                    scT[(size_t)(tx + 64) * MP + mrow[k]] = acc1[k];
                }
            }
            __syncthreads();

            // half B: j = 128..199 (72 rows; thread tx owns j=128+tx, j=192+tx if tx<8)
            for (int t = tid; t < 72 * 16; t += 256) {
                int r = t >> 4, q4 = t & 15;
                *(float4*)(bufA + r * 68 + q4 * 4) =
                    *(const float4*)(Kbase + (size_t)(128 + r) * Dc + q4 * 4);
            }
            __syncthreads();
            {
                float acc0[CPG], acc1[CPG];
                #pragma unroll
                for (int k = 0; k < CPG; ++k) { acc0[k] = 0.f; acc1[k] = 0.f; }
                #pragma unroll
                for (int d0 = 0; d0 < 16; ++d0) {
                    float4 k0 = *(const float4*)(bufA + tx * 68 + d0 * 4);
                    float4 k1 = *(const float4*)(bufA + (tx + 64) * 68 + d0 * 4);
                    #pragma unroll
                    for (int k = 0; k < CPG; ++k) {
                        float4 q = *(const float4*)(bufB + mrow[k] * 68 + d0 * 4);
                        acc0[k] += q.x*k0.x + q.y*k0.y + q.z*k0.z + q.w*k0.w;
                        acc1[k] += q.x*k1.x + q.y*k1.y + q.z*k1.z + q.w*k1.w;
                    }
                }
                #pragma unroll
                for (int k = 0; k < CPG; ++k) {
                    scT[(size_t)(128 + tx) * MP + mrow[k]] = acc0[k];
                    if (tx < 8) scT[(size_t)(192 + tx) * MP + mrow[k]] = acc1[k];
                }
            }
            __syncthreads();
        }
    }

    // ---- gate GEMM: Y[m][j] = sum_i scT[i][m] * Wf1[i][j]; then e[m]
    int mq, jq; bool gact;
    if (CH == 9) { mq = tid / 25; jq = tid - mq * 25; gact = (tid < 225); }
    else         { mq = tid / 50; jq = tid - mq * 50; gact = (tid < 200); }

    float gacc[4][4 * NQ];
    #pragma unroll
    for (int r = 0; r < 4; ++r)
        #pragma unroll
        for (int jj = 0; jj < 4 * NQ; ++jj) gacc[r][jj] = 0.f;

    float* Ws  = bufA;
    float* red = bufA + 16 * 200;

    for (int i0 = 0; i0 < Sc; i0 += 16) {
        const int nrow = (Sc - i0 < 16) ? (Sc - i0) : 16;
        for (int t = tid; t < nrow * 50; t += 256)
            ((float4*)Ws)[t] = ((const float4*)Wf1)[i0 * 50 + t];
        __syncthreads();
        if (gact) {
            for (int ii = 0; ii < nrow; ++ii) {
                const float4 a  = *(const float4*)(scT + (size_t)(i0 + ii) * MP + mq * 4);
                const float4 b0 = *(const float4*)(Ws + ii * 200 + jq * 4);
                float av[4]  = {a.x, a.y, a.z, a.w};
                float b0v[4] = {b0.x, b0.y, b0.z, b0.w};
                #pragma unroll
                for (int r = 0; r < 4; ++r)
                    #pragma unroll
                    for (int jj = 0; jj < 4; ++jj)
                        gacc[r][jj] += av[r] * b0v[jj];
                if constexpr (NQ == 2) {
                    const float4 b1 = *(const float4*)(Ws + ii * 200 + 100 + jq * 4);
                    float b1v[4] = {b1.x, b1.y, b1.z, b1.w};
                    #pragma unroll
                    for (int r = 0; r < 4; ++r)
                        #pragma unroll
                        for (int jj = 0; jj < 4; ++jj)
                            gacc[r][4 + jj] += av[r] * b1v[jj];
                }
            }
        }
        __syncthreads();
    }

    // e partials: relu(Y + bf1) . Wf2
    if (gact) {
        #pragma unroll
        for (int r = 0; r < 4; ++r) {
            float s = 0.f;
            #pragma unroll
            for (int jj = 0; jj < 4 * NQ; ++jj) {
                int j = (jj < 4) ? (jq * 4 + jj) : (100 + jq * 4 + (jj - 4));
                s += fmaxf(gacc[r][jj] + bf1[j], 0.f) * Wf2[j];
            }
            red[(mq * 4 + r) * RW + jq] = s;
        }
    }
    __syncthreads();
    if (tid < M) {
        float e = bf2p[0];
        for (int q = 0; q < JQn; ++q) e += red[tid * RW + q];
        evals[tid] = e;
    }
    __syncthreads();
    // channel softmax per row r
    if (tid < R) {
        float mx = -1e30f;
        #pragma unroll
        for (int c = 0; c < CH; ++c) mx = fmaxf(mx, evals[c * 4 + tid]);
        float ex[CH]; float s = 0.f;
        #pragma unroll
        for (int c = 0; c < CH; ++c) { ex[c] = __expf(evals[c * 4 + tid] - mx); s += ex[c]; }
        float inv = 1.f / s;
        #pragma unroll
        for (int c = 0; c < CH; ++c) wch[c * 4 + tid] = ex[c] * inv;
    }
    __syncthreads();

    // ---- gated sum + scale + mask -> gbuf[4][200]
    float* gbuf = bufB;
    if (tid < Sc) {
        float gr[4] = {0.f, 0.f, 0.f, 0.f};
        #pragma unroll
        for (int c = 0; c < CH; ++c) {
            float4 sv = *(const float4*)(scT + (size_t)tid * MP + c * 4);
            gr[0] += wch[c * 4 + 0] * sv.x;
            gr[1] += wch[c * 4 + 1] * sv.y;
            gr[2] += wch[c * 4 + 2] * sv.z;
            gr[3] += wch[c * 4 + 3] * sv.w;
        }
        const float* mrow = mask + ((size_t)b * Sc + r0) * Sc;
        #pragma unroll
        for (int r = 0; r < 4; ++r)
            gbuf[r * 200 + tid] = gr[r] * SCALE + mrow[(size_t)r * Sc + tid];
    }
    __syncthreads();

    // ---- row softmax: wave ty owns row ty
    {
        const int r = ty;
        float vals[4]; float mpart = -1e30f;
        #pragma unroll
        for (int t4 = 0; t4 < 4; ++t4) {
            int j = t4 * 64 + tx;
            vals[t4] = (j < Sc) ? gbuf[r * 200 + j] : -1e30f;
            mpart = fmaxf(mpart, vals[t4]);
        }
        #pragma unroll
        for (int off = 32; off >= 1; off >>= 1) mpart = fmaxf(mpart, __shfl_xor(mpart, off, 64));
        float spart = 0.f;
        #pragma unroll
        for (int t4 = 0; t4 < 4; ++t4) {
            int j = t4 * 64 + tx;
            if (j < Sc) {
                float exv = __expf(vals[t4] - mpart);
                gbuf[r * 200 + j] = exv;
                spart += exv;
            }
        }
        #pragma unroll
        for (int off = 32; off >= 1; off >>= 1) spart += __shfl_xor(spart, off, 64);
        float inv = 1.f / spart;
        #pragma unroll
        for (int t4 = 0; t4 < 4; ++t4) {
            int j = t4 * 64 + tx;
            if (j < Sc) gbuf[r * 200 + j] *= inv;
        }
    }
    // wave-local: no sync needed (each wave reads only its own row below)

    // ---- PV: ctx[r][d] = sum_j p[r][j] * V[j][d]
    {
        const int r = ty, d = tx;
        const float* vb = proj_ws + (size_t)vproj * NPc * Dc + (size_t)(b * Sc) * Dc + h * HDc + d;
        float a0 = 0.f, a1 = 0.f, a2 = 0.f, a3 = 0.f;
        for (int j = 0; j < Sc; j += 4) {
            a0 += gbuf[r * 200 + j    ] * vb[(size_t)(j    ) * Dc];
            a1 += gbuf[r * 200 + j + 1] * vb[(size_t)(j + 1) * Dc];
            a2 += gbuf[r * 200 + j + 2] * vb[(size_t)(j + 2) * Dc];
            a3 += gbuf[r * 200 + j + 3] * vb[(size_t)(j + 3) * Dc];
        }
        ctx_out[((size_t)(b * Sc + r0 + r)) * Dc + h * HDc + d] = a0 + a1 + a2 + a3;
    }
}

// ---------------------------------------------------------------------------
// Kernel 3: out = LayerNorm( A @ W + bias + resid ) * gamma + beta
// ---------------------------------------------------------------------------
__global__ __launch_bounds__(256) void out_ln_kernel(
    const float* __restrict__ Actx,
    const float* __restrict__ W,
    const float* __restrict__ bias,
    const float* __restrict__ resid,
    const float* __restrict__ gamma,
    const float* __restrict__ beta,
    float* __restrict__ out)
{
    const int m0 = blockIdx.x * 16;
    const int tid = threadIdx.x;

    __shared__ float As[16][256];
    __shared__ float ylds[16][256];

    for (int t = tid; t < 16 * 64; t += 256) {
        int r = t >> 6, k4 = t & 63;
        ((float4*)As[r])[k4] = ((const float4*)(Actx + (size_t)(m0 + r) * Dc))[k4];
    }
    __syncthreads();

    float acc[16];
    #pragma unroll
    for (int r = 0; r < 16; r++) acc[r] = 0.f;

    for (int k = 0; k < 256; k += 4) {
        float w0 = W[(size_t)(k    ) * Dc + tid];
        float w1 = W[(size_t)(k + 1) * Dc + tid];
        float w2 = W[(size_t)(k + 2) * Dc + tid];
        float w3 = W[(size_t)(k + 3) * Dc + tid];
        #pragma unroll
        for (int r = 0; r < 16; r++) {
            float4 a4 = ((float4*)As[r])[k >> 2];
            acc[r] += a4.x * w0 + a4.y * w1 + a4.z * w2 + a4.w * w3;
        }
    }

    const float bv = bias[tid];
    #pragma unroll
    for (int r = 0; r < 16; r++) {
        ylds[r][tid] = acc[r] + bv + resid[(size_t)(m0 + r) * Dc + tid];
    }
    __syncthreads();

    const int lane = tid & 63;
    const int wv   = tid >> 6;
    for (int r = wv * 4; r < wv * 4 + 4; r++) {
        float v4[4];
        float s = 0.f, s2 = 0.f;
        #pragma unroll
        for (int t4 = 0; t4 < 4; t4++) {
            float v = ylds[r][t4 * 64 + lane];
            v4[t4] = v;
            s += v;
            s2 += v * v;
        }
        #pragma unroll
        for (int off = 32; off >= 1; off >>= 1) {
            s  += __shfl_xor(s, off, 64);
            s2 += __shfl_xor(s2, off, 64);
        }
        float m   = s * (1.f / 256.f);
        float var = s2 * (1.f / 256.f) - m * m;
        float rstd = rsqrtf(var + 1e-12f);
        #pragma unroll
        for (int t4 = 0; t4 < 4; t4++) {
            int ccol = t4 * 64 + lane;
            out[(size_t)(m0 + r) * Dc + ccol] = (v4[t4] - m) * rstd * gamma[ccol] + beta[ccol];
        }
    }
}

// ---------------------------------------------------------------------------
// Launcher
// ---------------------------------------------------------------------------
extern "C" void kernel_launch(void* const* d_in, const int* in_sizes, int n_in,
                              void* d_out, int out_size, void* d_ws, size_t ws_size,
                              hipStream_t stream) {
    const float* X    = (const float*)d_in[0];
    const float* AT   = (const float*)d_in[1];
    const float* P    = (const float*)d_in[2];
    const float* HA   = (const float*)d_in[3];
    const float* mask = (const float*)d_in[4];
    const float* fw   = (const float*)d_in[5];
    const float* fwc  = (const float*)d_in[6];

    const float* Wq   = (const float*)d_in[7];
    const float* bq   = (const float*)d_in[8];
    const float* Wk   = (const float*)d_in[9];
    const float* bk   = (const float*)d_in[10];
    const float* Wv   = (const float*)d_in[11];
    const float* bv   = (const float*)d_in[12];
    const float* Wqp  = (const float*)d_in[13];
    const float* bqp  = (const float*)d_in[14];
    const float* Wkp  = (const float*)d_in[15];
    const float* bkp  = (const float*)d_in[16];
    const float* Waq  = (const float*)d_in[17];
    const float* baq  = (const float*)d_in[18];
    const float* Wak  = (const float*)d_in[19];
    const float* bak  = (const float*)d_in[20];
    const float* Wav  = (const float*)d_in[21];
    const float* bav  = (const float*)d_in[22];
    const float* Wqic = (const float*)d_in[23];
    const float* bqic = (const float*)d_in[24];
    const float* Wqci = (const float*)d_in[25];
    const float* bqci = (const float*)d_in[26];
    const float* Wqpc = (const float*)d_in[27];
    const float* bqpc = (const float*)d_in[28];
    const float* Wqcp = (const float*)d_in[29];
    const float* bqcp = (const float*)d_in[30];
    const float* Wf1  = (const float*)d_in[31];
    const float* bf1  = (const float*)d_in[32];
    const float* Wf2  = (const float*)d_in[33];
    const float* bf2  = (const float*)d_in[34];
    const float* Wd   = (const float*)d_in[35];
    const float* bd   = (const float*)d_in[36];
    const float* ln_g = (const float*)d_in[37];
    const float* ln_b = (const float*)d_in[38];
    const float* Wda  = (const float*)d_in[39];
    const float* bda  = (const float*)d_in[40];
    const float* lna_g= (const float*)d_in[41];
    const float* lna_b= (const float*)d_in[42];

    float* wsf = (float*)d_ws;
    float* proj_ws = wsf;
    size_t off = (size_t)NPROJ * NPc * Dc;
    float* ctx  = wsf + off;  off += (size_t)NPc * Dc;
    float* ctxc = wsf + off;  off += (size_t)NPc * Dc;

    ProjArgs pa;
    const float* Amat[NPROJ] = {X, X, X, P, P, AT, AT, HA, HA, HA, X, AT, AT, HA, P};
    const float* Wmat[NPROJ] = {Wq, Wk, Wv, Wqp, Wkp, Waq, Wak, Waq, Wak, Wav, Wqic, Wqci, Wqcp, Wqcp, Wqpc};
    const float* bmat[NPROJ] = {bq, bk, bv, bqp, bkp, baq, bak, baq, bak, bav, bqic, bqci, bqcp, bqcp, bqpc};
    for (int i = 0; i < NPROJ; i++) { pa.A[i] = Amat[i]; pa.W[i] = Wmat[i]; pa.bias[i] = bmat[i]; }

    // 1. projections
    proj_kernel<<<dim3(NPc / 32, NPROJ), 256, 0, stream>>>(pa, proj_ws);

    // 2. fused attention
    fused2<9><<<Bc * Hc * (Sc / 4), 256, 0, stream>>>(
        proj_ws, fw, mask, Wf1, bf1, Wf2, bf2, ctx, 2);
    fused2<4><<<Bc * Hc * (Sc / 4), 256, 0, stream>>>(
        proj_ws, fwc, mask, Wf1, bf1, Wf2, bf2, ctxc, 9);

    // 3. output projections + residual + LayerNorm
    float* out0 = (float*)d_out;
    float* out1 = out0 + (size_t)NPc * Dc;
    out_ln_kernel<<<NPc / 16, 256, 0, stream>>>(ctx,  Wd,  bd,  X,  ln_g,  ln_b,  out0);
    out_ln_kernel<<<NPc / 16, 256, 0, stream>>>(ctxc, Wda, bda, HA, lna_g, lna_b, out1);
}

// Round 3
// 1025.839 us; speedup vs baseline: 10.3545x; 3.2604x over previous
//
#include <hip/hip_runtime.h>
#include <cstddef>

typedef __attribute__((ext_vector_type(8))) short bf16x8;
typedef __attribute__((ext_vector_type(4))) short bf16x4;
typedef __attribute__((ext_vector_type(4))) float f32x4;

constexpr int Bc = 64;
constexpr int Sc = 200;
constexpr int Hc = 4;
constexpr int Dc = 256;
constexpr int HDc = 64;
constexpr int NPc = Bc * Sc;          // 12800 rows
constexpr int NPROJ = 15;
constexpr float SCALE = 0.125f;       // 1/sqrt(64)

// proj indices
// 0 iq, 1 ik, 2 iv, 3 pq, 4 pk, 5 aq, 6 ak, 7 haq, 8 hak, 9 hav,
// 10 iqc, 11 ciq, 12 cqp, 13 cqp_a, 14 pqc

// 9-channel: groups by shared K tensor. group g slot k -> channel c = CG[g*CPG+k]
__constant__ int c_KP9[3]  = {1,6,4};                   // K proj per group
__constant__ int c_QP9[9]  = {0,11,3, 10,5,14, 0,12,3}; // Q proj per (g,k) slot
__constant__ int c_CG9[9]  = {0,3,6, 1,4,7, 2,5,8};     // slot -> channel
__constant__ int c_M2S9[9] = {0,12,24,4,16,28,8,20,32}; // channel -> compact S row base
__constant__ int c_KP4[2]  = {8,4};
__constant__ int c_QP4[4]  = {7,14, 13,3};
__constant__ int c_CG4[4]  = {0,2, 1,3};
__constant__ int c_M2S4[4] = {0,8,4,12};

__device__ __forceinline__ short f2bf(float x) {
    union { float f; unsigned u; } v; v.f = x;
    unsigned r = v.u + 0x7FFFu + ((v.u >> 16) & 1u);
    return (short)(r >> 16);
}
__device__ __forceinline__ float bf2f(short x) {
    union { unsigned u; float f; } v; v.u = ((unsigned)(unsigned short)x) << 16;
    return v.f;
}
__device__ __forceinline__ f32x4 mfma16(bf16x8 a, bf16x8 b, f32x4 c) {
    return __builtin_amdgcn_mfma_f32_16x16x32_bf16(a, b, c, 0, 0, 0);
}

struct ProjArgs {
    const float* A[NPROJ];
    const float* W[NPROJ];
    const float* bias[NPROJ];
    float*       outf[NPROJ];   // fp32 output (only V tensors), else nullptr
};

// ---------------------------------------------------------------------------
// Kernel 1: all 15 projections -> bf16 (always) + fp32 (V tensors only)
// ---------------------------------------------------------------------------
__global__ __launch_bounds__(256) void proj_kernel(ProjArgs args, short* __restrict__ proj_bf) {
    const int p  = blockIdx.y;
    const int m0 = blockIdx.x * 32;
    const float* __restrict__ A    = args.A[p];
    const float* __restrict__ W    = args.W[p];
    const float* __restrict__ bias = args.bias[p];
    float* __restrict__ of = args.outf[p];
    short* __restrict__ ob = proj_bf + (size_t)p * NPc * Dc;

    __shared__ float As[32][256];
    const int tid = threadIdx.x;

    for (int t = tid; t < 32 * 64; t += 256) {
        int r = t >> 6, k4 = t & 63;
        ((float4*)As[r])[k4] = ((const float4*)(A + (size_t)(m0 + r) * Dc))[k4];
    }
    __syncthreads();

    const int tx = tid & 63;
    const int ty = tid >> 6;

    float acc[8][4];
    #pragma unroll
    for (int i = 0; i < 8; i++)
        #pragma unroll
        for (int j = 0; j < 4; j++) acc[i][j] = 0.f;

    for (int k = 0; k < 256; k += 4) {
        float4 w0 = ((const float4*)(W + (size_t)(k    ) * Dc))[tx];
        float4 w1 = ((const float4*)(W + (size_t)(k + 1) * Dc))[tx];
        float4 w2 = ((const float4*)(W + (size_t)(k + 2) * Dc))[tx];
        float4 w3 = ((const float4*)(W + (size_t)(k + 3) * Dc))[tx];
        #pragma unroll
        for (int rr = 0; rr < 8; rr++) {
            int r = ty + rr * 4;
            float4 a4 = ((float4*)As[r])[k >> 2];
            acc[rr][0] += a4.x * w0.x + a4.y * w1.x + a4.z * w2.x + a4.w * w3.x;
            acc[rr][1] += a4.x * w0.y + a4.y * w1.y + a4.z * w2.y + a4.w * w3.y;
            acc[rr][2] += a4.x * w0.z + a4.y * w1.z + a4.z * w2.z + a4.w * w3.z;
            acc[rr][3] += a4.x * w0.w + a4.y * w1.w + a4.z * w2.w + a4.w * w3.w;
        }
    }

    float4 bv = ((const float4*)bias)[tx];
    #pragma unroll
    for (int rr = 0; rr < 8; rr++) {
        int r = ty + rr * 4;
        float4 o;
        o.x = acc[rr][0] + bv.x;
        o.y = acc[rr][1] + bv.y;
        o.z = acc[rr][2] + bv.z;
        o.w = acc[rr][3] + bv.w;
        bf16x4 b4;
        b4[0] = f2bf(o.x); b4[1] = f2bf(o.y); b4[2] = f2bf(o.z); b4[3] = f2bf(o.w);
        *(bf16x4*)(ob + ((size_t)(m0 + r)) * Dc + tx * 4) = b4;
        if (of) ((float4*)(of + (size_t)(m0 + r) * Dc))[tx] = o;
    }
}

// ---------------------------------------------------------------------------
// Kernel 1b: Wf1 (200x200 f32) -> WT bf16 [224][224], WT[j][i] = Wf1[i][j], 0-pad
// ---------------------------------------------------------------------------
__global__ void wf1t_kernel(const float* __restrict__ Wf1, short* __restrict__ WT) {
    int t = blockIdx.x * 256 + threadIdx.x;
    if (t < 224 * 224) {
        int j = t / 224, i = t % 224;
        WT[t] = (i < Sc && j < Sc) ? f2bf(Wf1[(size_t)i * Sc + j]) : (short)0;
    }
}

// ---------------------------------------------------------------------------
// Kernel 2 (v3): MFMA scores + MFMA gate + channel softmax + row softmax + PV
// One block = (b, h, 4 rows). grid = 12800 x 256 threads.
// ---------------------------------------------------------------------------
template <int CH, int NG, int CPG>
__global__ __launch_bounds__(256) void fused3(
    const short* __restrict__ proj_bf,
    const float* __restrict__ vf32,      // V tensor fp32 [NPc][256]
    const float* __restrict__ fw,
    const float* __restrict__ mask,
    const short* __restrict__ WT,        // [224][224] bf16 (Wf1 transposed, 0-pad)
    const float* __restrict__ bf1,
    const float* __restrict__ Wf2,
    float* __restrict__ ctx_out)
{
    constexpr int M2    = NG * CPG * 4;       // 36 (CH9) / 16 (CH4): compact S rows
    constexpr int MT2   = (M2 + 15) / 16;     // gate M-tiles: 3 / 1
    constexpr int SROWS = MT2 * 16;           // 48 / 16
    constexpr int SLD   = 232;                // S row stride (bf16), bank-friendly
    constexpr int QROWS = NG * 16;
    constexpr int QLD   = 72;
    constexpr int PADR  = 16 - CPG * 4;       // pad rows per q group

    __shared__ __align__(16) short Sl[SROWS * SLD];   // scores bf16 (fw folded)
    __shared__ __align__(16) short Ql[QROWS * QLD];   // q bf16 per group-slot
    __shared__ float gbuf[4][200];
    __shared__ float evw[4][SROWS];                   // per-wave gate partials
    __shared__ float wch[M2];
    __shared__ float fwl[CH];

    const int tid = threadIdx.x;
    const int bid = blockIdx.x;
    const int rt  = bid % 50;
    const int h   = (bid / 50) & 3;
    const int b   = bid / 200;
    const int r0  = rt * 4;
    const int lane = tid & 63, wv = tid >> 6;
    const int l15 = lane & 15, l4 = lane >> 4;

    const int* KP  = (CH == 9) ? c_KP9  : c_KP4;
    const int* QP  = (CH == 9) ? c_QP9  : c_QP4;
    const int* CG  = (CH == 9) ? c_CG9  : c_CG4;
    const int* M2S = (CH == 9) ? c_M2S9 : c_M2S4;

    // ---- phase 0: zero S fully; zero q pad rows; fill q valid rows; load fw
    {
        bf16x8 z = {};
        for (int t = tid; t < SROWS * SLD / 8; t += 256) ((bf16x8*)Sl)[t] = z;
        for (int t = tid; t < NG * PADR * (QLD / 8); t += 256) {
            int g   = t / (PADR * (QLD / 8));
            int rem = t % (PADR * (QLD / 8));
            int pr  = rem / (QLD / 8);
            int ck  = rem % (QLD / 8);
            ((bf16x8*)(Ql + (g * 16 + CPG * 4 + pr) * QLD))[ck] = z;
        }
        for (int t = tid; t < NG * CPG * 4 * 8; t += 256) {
            int s  = t >> 5;            // slot (g,k)
            int rr = (t >> 3) & 3;
            int ck = t & 7;
            int g = s / CPG, k = s % CPG;
            const short* src = proj_bf + ((size_t)QP[s] * NPc + (size_t)(b * Sc + r0 + rr)) * Dc + h * HDc + ck * 8;
            *(bf16x8*)(Ql + (g * 16 + k * 4 + rr) * QLD + ck * 8) = *(const bf16x8*)src;
        }
        if (tid < CH) fwl[tid] = fw[tid];
    }
    __syncthreads();

    // ---- scores: S[m2][j] = fw[c] * (q_m . k_j), via MFMA, written bf16 to Sl
    {
        // preload A-fragments: a[g][kstep]
        bf16x8 af[NG][2];
        #pragma unroll
        for (int g = 0; g < NG; ++g)
            #pragma unroll
            for (int ks = 0; ks < 2; ++ks)
                af[g][ks] = *(const bf16x8*)(Ql + (g * 16 + l15) * QLD + ks * 32 + l4 * 8);

        const bool kval = (l4 < CPG);
        float fwv[NG];
        #pragma unroll
        for (int g = 0; g < NG; ++g) {
            int cidx = kval ? (g * CPG + l4) : 0;
            fwv[g] = kval ? fwl[CG[cidx]] : 0.f;
        }

        for (int nt = wv; nt < 13; nt += 4) {
            int j = nt * 16 + l15;   // 0..207
            #pragma unroll
            for (int g = 0; g < NG; ++g) {
                const short* Kb = proj_bf + ((size_t)KP[g] * NPc + (size_t)(b * Sc)) * Dc + h * HDc;
                f32x4 c = {};
                #pragma unroll
                for (int ks = 0; ks < 2; ++ks) {
                    bf16x8 bfr = *(const bf16x8*)(Kb + (size_t)j * Dc + ks * 32 + l4 * 8);
                    c = mfma16(af[g][ks], bfr, c);
                }
                if (j < Sc && kval) {
                    int m2b = g * (CPG * 4) + l4 * 4;
                    #pragma unroll
                    for (int i = 0; i < 4; ++i)
                        Sl[(m2b + i) * SLD + j] = f2bf(c[i] * fwv[g]);
                }
            }
        }
    }
    __syncthreads();

    // ---- gate: Y[m][j] = sum_i S[m][i]*Wf1[i][j]; e[m] = sum_j relu(Y+bf1)*Wf2
    {
        float epart[MT2 * 4];
        #pragma unroll
        for (int q = 0; q < MT2 * 4; ++q) epart[q] = 0.f;

        for (int nt = wv; nt < 13; nt += 4) {
            int j2 = nt * 16 + l15;      // WT row (< 224)
            f32x4 cg[MT2];
            #pragma unroll
            for (int mt = 0; mt < MT2; ++mt) cg[mt] = (f32x4){};
            #pragma unroll
            for (int ks = 0; ks < 7; ++ks) {
                bf16x8 bb = *(const bf16x8*)(WT + (size_t)j2 * 224 + ks * 32 + l4 * 8);
                #pragma unroll
                for (int mt = 0; mt < MT2; ++mt) {
                    bf16x8 aa = *(const bf16x8*)(Sl + (mt * 16 + l15) * SLD + ks * 32 + l4 * 8);
                    cg[mt] = mfma16(aa, bb, cg[mt]);
                }
            }
            int j = nt * 16 + l15;
            float b1 = (j < Sc) ? bf1[j] : 0.f;
            float w2 = (j < Sc) ? Wf2[j] : 0.f;
            #pragma unroll
            for (int mt = 0; mt < MT2; ++mt) {
                #pragma unroll
                for (int i = 0; i < 4; ++i) {
                    float v = fmaxf(cg[mt][i] + b1, 0.f) * w2;
                    v += __shfl_xor(v, 1, 64);
                    v += __shfl_xor(v, 2, 64);
                    v += __shfl_xor(v, 4, 64);
                    v += __shfl_xor(v, 8, 64);
                    epart[mt * 4 + i] += v;
                }
            }
        }
        if (l15 == 0) {
            #pragma unroll
            for (int mt = 0; mt < MT2; ++mt)
                #pragma unroll
                for (int i = 0; i < 4; ++i)
                    evw[wv][mt * 16 + l4 * 4 + i] = epart[mt * 4 + i];
        }
    }
    __syncthreads();

    // ---- channel softmax per row (bf2 dropped: softmax shift-invariant)
    if (tid < 4) {
        int r = tid;
        float e[CH]; float mx = -1e30f;
        #pragma unroll
        for (int c = 0; c < CH; ++c) {
            float s = 0.f;
            #pragma unroll
            for (int w = 0; w < 4; ++w) s += evw[w][M2S[c] + r];
            e[c] = s; mx = fmaxf(mx, s);
        }
        float sum = 0.f;
        #pragma unroll
        for (int c = 0; c < CH; ++c) { e[c] = __expf(e[c] - mx); sum += e[c]; }
        float inv = 1.f / sum;
        #pragma unroll
        for (int c = 0; c < CH; ++c) wch[M2S[c] + r] = e[c] * inv;
    }
    __syncthreads();

    // ---- gated sum + scale + mask -> gbuf
    if (tid < Sc) {
        int j = tid;
        const float* mrow = mask + ((size_t)b * Sc + r0) * Sc;
        #pragma unroll
        for (int r = 0; r < 4; ++r) {
            float acc = 0.f;
            #pragma unroll
            for (int c = 0; c < CH; ++c)
                acc += wch[M2S[c] + r] * bf2f(Sl[(M2S[c] + r) * SLD + j]);
            gbuf[r][j] = acc * SCALE + mrow[(size_t)r * Sc + j];
        }
    }
    __syncthreads();

    // ---- row softmax (wave wv owns row wv)
    {
        const int r = wv, tx = lane;
        float vals[4]; float mpart = -1e30f;
        #pragma unroll
        for (int t4 = 0; t4 < 4; ++t4) {
            int j = t4 * 64 + tx;
            vals[t4] = (j < Sc) ? gbuf[r][j] : -1e30f;
            mpart = fmaxf(mpart, vals[t4]);
        }
        #pragma unroll
        for (int off = 32; off >= 1; off >>= 1) mpart = fmaxf(mpart, __shfl_xor(mpart, off, 64));
        float spart = 0.f;
        #pragma unroll
        for (int t4 = 0; t4 < 4; ++t4) {
            int j = t4 * 64 + tx;
            if (j < Sc) {
                float exv = __expf(vals[t4] - mpart);
                gbuf[r][j] = exv;
                spart += exv;
            }
        }
        #pragma unroll
        for (int off = 32; off >= 1; off >>= 1) spart += __shfl_xor(spart, off, 64);
        float inv = 1.f / spart;
        #pragma unroll
        for (int t4 = 0; t4 < 4; ++t4) {
            int j = t4 * 64 + tx;
            if (j < Sc) gbuf[r][j] *= inv;
        }
    }
    // wave-local from here: no sync needed

    // ---- PV: ctx[r][d] = sum_j p[r][j] * V[j][d]  (fp32 V)
    {
        const int r = wv, d = lane;
        const float* vb = vf32 + (size_t)(b * Sc) * Dc + h * HDc + d;
        float a0 = 0.f, a1 = 0.f, a2 = 0.f, a3 = 0.f;
        for (int j = 0; j < Sc; j += 4) {
            a0 += gbuf[r][j    ] * vb[(size_t)(j    ) * Dc];
            a1 += gbuf[r][j + 1] * vb[(size_t)(j + 1) * Dc];
            a2 += gbuf[r][j + 2] * vb[(size_t)(j + 2) * Dc];
            a3 += gbuf[r][j + 3] * vb[(size_t)(j + 3) * Dc];
        }
        ctx_out[((size_t)(b * Sc + r0 + r)) * Dc + h * HDc + d] = a0 + a1 + a2 + a3;
    }
}

// ---------------------------------------------------------------------------
// Kernel 3: out = LayerNorm( A @ W + bias + resid ) * gamma + beta
// ---------------------------------------------------------------------------
__global__ __launch_bounds__(256) void out_ln_kernel(
    const float* __restrict__ Actx,
    const float* __restrict__ W,
    const float* __restrict__ bias,
    const float* __restrict__ resid,
    const float* __restrict__ gamma,
    const float* __restrict__ beta,
    float* __restrict__ out)
{
    const int m0 = blockIdx.x * 16;
    const int tid = threadIdx.x;

    __shared__ float As[16][256];
    __shared__ float ylds[16][256];

    for (int t = tid; t < 16 * 64; t += 256) {
        int r = t >> 6, k4 = t & 63;
        ((float4*)As[r])[k4] = ((const float4*)(Actx + (size_t)(m0 + r) * Dc))[k4];
    }
    __syncthreads();

    float acc[16];
    #pragma unroll
    for (int r = 0; r < 16; r++) acc[r] = 0.f;

    for (int k = 0; k < 256; k += 4) {
        float w0 = W[(size_t)(k    ) * Dc + tid];
        float w1 = W[(size_t)(k + 1) * Dc + tid];
        float w2 = W[(size_t)(k + 2) * Dc + tid];
        float w3 = W[(size_t)(k + 3) * Dc + tid];
        #pragma unroll
        for (int r = 0; r < 16; r++) {
            float4 a4 = ((float4*)As[r])[k >> 2];
            acc[r] += a4.x * w0 + a4.y * w1 + a4.z * w2 + a4.w * w3;
        }
    }

    const float bv = bias[tid];
    #pragma unroll
    for (int r = 0; r < 16; r++) {
        ylds[r][tid] = acc[r] + bv + resid[(size_t)(m0 + r) * Dc + tid];
    }
    __syncthreads();

    const int lane = tid & 63;
    const int wv   = tid >> 6;
    for (int r = wv * 4; r < wv * 4 + 4; r++) {
        float v4[4];
        float s = 0.f, s2 = 0.f;
        #pragma unroll
        for (int t4 = 0; t4 < 4; t4++) {
            float v = ylds[r][t4 * 64 + lane];
            v4[t4] = v;
            s += v;
            s2 += v * v;
        }
        #pragma unroll
        for (int off = 32; off >= 1; off >>= 1) {
            s  += __shfl_xor(s, off, 64);
            s2 += __shfl_xor(s2, off, 64);
        }
        float m   = s * (1.f / 256.f);
        float var = s2 * (1.f / 256.f) - m * m;
        float rstd = rsqrtf(var + 1e-12f);
        #pragma unroll
        for (int t4 = 0; t4 < 4; t4++) {
            int ccol = t4 * 64 + lane;
            out[(size_t)(m0 + r) * Dc + ccol] = (v4[t4] - m) * rstd * gamma[ccol] + beta[ccol];
        }
    }
}

// ---------------------------------------------------------------------------
// Launcher
// ---------------------------------------------------------------------------
extern "C" void kernel_launch(void* const* d_in, const int* in_sizes, int n_in,
                              void* d_out, int out_size, void* d_ws, size_t ws_size,
                              hipStream_t stream) {
    const float* X    = (const float*)d_in[0];
    const float* AT   = (const float*)d_in[1];
    const float* P    = (const float*)d_in[2];
    const float* HA   = (const float*)d_in[3];
    const float* mask = (const float*)d_in[4];
    const float* fw   = (const float*)d_in[5];
    const float* fwc  = (const float*)d_in[6];

    const float* Wq   = (const float*)d_in[7];
    const float* bq   = (const float*)d_in[8];
    const float* Wk   = (const float*)d_in[9];
    const float* bk   = (const float*)d_in[10];
    const float* Wv   = (const float*)d_in[11];
    const float* bv   = (const float*)d_in[12];
    const float* Wqp  = (const float*)d_in[13];
    const float* bqp  = (const float*)d_in[14];
    const float* Wkp  = (const float*)d_in[15];
    const float* bkp  = (const float*)d_in[16];
    const float* Waq  = (const float*)d_in[17];
    const float* baq  = (const float*)d_in[18];
    const float* Wak  = (const float*)d_in[19];
    const float* bak  = (const float*)d_in[20];
    const float* Wav  = (const float*)d_in[21];
    const float* bav  = (const float*)d_in[22];
    const float* Wqic = (const float*)d_in[23];
    const float* bqic = (const float*)d_in[24];
    const float* Wqci = (const float*)d_in[25];
    const float* bqci = (const float*)d_in[26];
    const float* Wqpc = (const float*)d_in[27];
    const float* bqpc = (const float*)d_in[28];
    const float* Wqcp = (const float*)d_in[29];
    const float* bqcp = (const float*)d_in[30];
    const float* Wf1  = (const float*)d_in[31];
    const float* bf1  = (const float*)d_in[32];
    const float* Wf2  = (const float*)d_in[33];
    const float* bf2  = (const float*)d_in[34];
    const float* Wd   = (const float*)d_in[35];
    const float* bd   = (const float*)d_in[36];
    const float* ln_g = (const float*)d_in[37];
    const float* ln_b = (const float*)d_in[38];
    const float* Wda  = (const float*)d_in[39];
    const float* bda  = (const float*)d_in[40];
    const float* lna_g= (const float*)d_in[41];
    const float* lna_b= (const float*)d_in[42];

    char* w = (char*)d_ws;
    short* proj_bf = (short*)w;  w += (size_t)NPROJ * NPc * Dc * sizeof(short);
    short* WT      = (short*)w;  w += (size_t)224 * 224 * sizeof(short);
    float* viv     = (float*)w;  w += (size_t)NPc * Dc * sizeof(float);
    float* vhav    = (float*)w;  w += (size_t)NPc * Dc * sizeof(float);
    float* ctx     = (float*)w;  w += (size_t)NPc * Dc * sizeof(float);
    float* ctxc    = (float*)w;  w += (size_t)NPc * Dc * sizeof(float);

    ProjArgs pa;
    const float* Amat[NPROJ] = {X, X, X, P, P, AT, AT, HA, HA, HA, X, AT, AT, HA, P};
    const float* Wmat[NPROJ] = {Wq, Wk, Wv, Wqp, Wkp, Waq, Wak, Waq, Wak, Wav, Wqic, Wqci, Wqcp, Wqcp, Wqpc};
    const float* bmat[NPROJ] = {bq, bk, bv, bqp, bkp, baq, bak, baq, bak, bav, bqic, bqci, bqcp, bqcp, bqpc};
    for (int i = 0; i < NPROJ; i++) {
        pa.A[i] = Amat[i]; pa.W[i] = Wmat[i]; pa.bias[i] = bmat[i];
        pa.outf[i] = nullptr;
    }
    pa.outf[2] = viv;    // iv
    pa.outf[9] = vhav;   // hav

    // 1. projections (bf16 + fp32 for V)
    proj_kernel<<<dim3(NPc / 32, NPROJ), 256, 0, stream>>>(pa, proj_bf);

    // 1b. Wf1^T bf16 (zero-padded to 224x224)
    wf1t_kernel<<<(224 * 224 + 255) / 256, 256, 0, stream>>>(Wf1, WT);

    // 2. fused attention (MFMA scores+gate)
    fused3<9, 3, 3><<<Bc * Hc * (Sc / 4), 256, 0, stream>>>(
        proj_bf, viv, fw, mask, WT, bf1, Wf2, ctx);
    fused3<4, 2, 2><<<Bc * Hc * (Sc / 4), 256, 0, stream>>>(
        proj_bf, vhav, fwc, mask, WT, bf1, Wf2, ctxc);

    // 3. output projections + residual + LayerNorm
    float* out0 = (float*)d_out;
    float* out1 = out0 + (size_t)NPc * Dc;
    out_ln_kernel<<<NPc / 16, 256, 0, stream>>>(ctx,  Wd,  bd,  X,  ln_g,  ln_b,  out0);
    out_ln_kernel<<<NPc / 16, 256, 0, stream>>>(ctxc, Wda, bda, HA, lna_g, lna_b, out1);
}

// Round 4
// 893.495 us; speedup vs baseline: 11.8882x; 1.1481x over previous
//
#include <hip/hip_runtime.h>
#include <cstddef>

typedef __attribute__((ext_vector_type(8))) short bf16x8;
typedef __attribute__((ext_vector_type(4))) short bf16x4;
typedef __attribute__((ext_vector_type(4))) float f32x4;

constexpr int Bc = 64;
constexpr int Sc = 200;
constexpr int Hc = 4;
constexpr int Dc = 256;
constexpr int HDc = 64;
constexpr int NPc = Bc * Sc;          // 12800 rows
constexpr int NPROJ = 15;
constexpr float SCALE = 0.125f;       // 1/sqrt(64)

// proj indices
// 0 iq, 1 ik, 2 iv, 3 pq, 4 pk, 5 aq, 6 ak, 7 haq, 8 hak, 9 hav,
// 10 iqc, 11 ciq, 12 cqp, 13 cqp_a, 14 pqc

// 9-channel: groups by shared K tensor; 8 rows per (slot); GR=24 rows/group
__constant__ int c_KP9[3]  = {1,6,4};                   // K proj per group
__constant__ int c_QP9[9]  = {0,11,3, 10,5,14, 0,12,3}; // Q proj per (g,k) slot
__constant__ int c_CG9[9]  = {0,3,6, 1,4,7, 2,5,8};     // slot -> channel
__constant__ int c_M2S9[9] = {0,24,48,8,32,56,16,40,64};// channel -> S row base (g*24+k*8)
__constant__ int c_KP4[2]  = {8,4};
__constant__ int c_QP4[4]  = {7,14, 13,3};
__constant__ int c_CG4[4]  = {0,2, 1,3};
__constant__ int c_M2S4[4] = {0,16,8,24};               // g*16+k*8

__device__ __forceinline__ short f2bf(float x) {
    union { float f; unsigned u; } v; v.f = x;
    unsigned r = v.u + 0x7FFFu + ((v.u >> 16) & 1u);
    return (short)(r >> 16);
}
__device__ __forceinline__ float bf2f(short x) {
    union { unsigned u; float f; } v; v.u = ((unsigned)(unsigned short)x) << 16;
    return v.f;
}
__device__ __forceinline__ f32x4 mfma16(bf16x8 a, bf16x8 b, f32x4 c) {
    return __builtin_amdgcn_mfma_f32_16x16x32_bf16(a, b, c, 0, 0, 0);
}

struct ProjArgs {
    const float* A[NPROJ];
    const float* W[NPROJ];
    const float* bias[NPROJ];
    float*       outf[NPROJ];   // fp32 output (only V tensors), else nullptr
};

// ---------------------------------------------------------------------------
// Kernel 1: all 15 projections -> bf16 (always) + fp32 (V tensors only)
// ---------------------------------------------------------------------------
__global__ __launch_bounds__(256) void proj_kernel(ProjArgs args, short* __restrict__ proj_bf) {
    const int p  = blockIdx.y;
    const int m0 = blockIdx.x * 32;
    const float* __restrict__ A    = args.A[p];
    const float* __restrict__ W    = args.W[p];
    const float* __restrict__ bias = args.bias[p];
    float* __restrict__ of = args.outf[p];
    short* __restrict__ ob = proj_bf + (size_t)p * NPc * Dc;

    __shared__ float As[32][256];
    const int tid = threadIdx.x;

    for (int t = tid; t < 32 * 64; t += 256) {
        int r = t >> 6, k4 = t & 63;
        ((float4*)As[r])[k4] = ((const float4*)(A + (size_t)(m0 + r) * Dc))[k4];
    }
    __syncthreads();

    const int tx = tid & 63;
    const int ty = tid >> 6;

    float acc[8][4];
    #pragma unroll
    for (int i = 0; i < 8; i++)
        #pragma unroll
        for (int j = 0; j < 4; j++) acc[i][j] = 0.f;

    for (int k = 0; k < 256; k += 4) {
        float4 w0 = ((const float4*)(W + (size_t)(k    ) * Dc))[tx];
        float4 w1 = ((const float4*)(W + (size_t)(k + 1) * Dc))[tx];
        float4 w2 = ((const float4*)(W + (size_t)(k + 2) * Dc))[tx];
        float4 w3 = ((const float4*)(W + (size_t)(k + 3) * Dc))[tx];
        #pragma unroll
        for (int rr = 0; rr < 8; rr++) {
            int r = ty + rr * 4;
            float4 a4 = ((float4*)As[r])[k >> 2];
            acc[rr][0] += a4.x * w0.x + a4.y * w1.x + a4.z * w2.x + a4.w * w3.x;
            acc[rr][1] += a4.x * w0.y + a4.y * w1.y + a4.z * w2.y + a4.w * w3.y;
            acc[rr][2] += a4.x * w0.z + a4.y * w1.z + a4.z * w2.z + a4.w * w3.z;
            acc[rr][3] += a4.x * w0.w + a4.y * w1.w + a4.z * w2.w + a4.w * w3.w;
        }
    }

    float4 bv = ((const float4*)bias)[tx];
    #pragma unroll
    for (int rr = 0; rr < 8; rr++) {
        int r = ty + rr * 4;
        float4 o;
        o.x = acc[rr][0] + bv.x;
        o.y = acc[rr][1] + bv.y;
        o.z = acc[rr][2] + bv.z;
        o.w = acc[rr][3] + bv.w;
        bf16x4 b4;
        b4[0] = f2bf(o.x); b4[1] = f2bf(o.y); b4[2] = f2bf(o.z); b4[3] = f2bf(o.w);
        *(bf16x4*)(ob + ((size_t)(m0 + r)) * Dc + tx * 4) = b4;
        if (of) ((float4*)(of + (size_t)(m0 + r) * Dc))[tx] = o;
    }
}

// ---------------------------------------------------------------------------
// Kernel 1b: Wf1 (200x200 f32) -> WT bf16 [224][224], WT[j][i] = Wf1[i][j], 0-pad
// ---------------------------------------------------------------------------
__global__ void wf1t_kernel(const float* __restrict__ Wf1, short* __restrict__ WT) {
    int t = blockIdx.x * 256 + threadIdx.x;
    if (t < 224 * 224) {
        int j = t / 224, i = t % 224;
        WT[t] = (i < Sc && j < Sc) ? f2bf(Wf1[(size_t)i * Sc + j]) : (short)0;
    }
}

// ---------------------------------------------------------------------------
// fused body (R = 8 rows per block)
// ---------------------------------------------------------------------------
template <int CH, int NG, int CPG, int QT, int MT2>
__device__ void fused_body(
    int bid,
    const short* __restrict__ proj_bf,
    const float* __restrict__ vf32,
    const float* __restrict__ fw,
    const float* __restrict__ mask,
    const short* __restrict__ WT,
    const float* __restrict__ bf1,
    const float* __restrict__ Wf2,
    float* __restrict__ ctx_out,
    const int* KP, const int* QP, const int* CG, const int* M2S,
    short* Sl, float* gbuf, float* evw, float* wch, float* fwl,
    float* bf1l, float* wf2l)
{
    constexpr int GR    = CPG * 8;     // valid S rows per group
    constexpr int SROWS = MT2 * 16;
    constexpr int SLD   = 232;
    constexpr int R     = 8;

    const int tid = threadIdx.x;
    const int rt  = bid % 25;          // 25 row-tiles of 8
    const int h   = (bid / 25) & 3;
    const int b   = bid / 100;
    const int r0  = rt * 8;
    const int lane = tid & 63, wv = tid >> 6;
    const int l15 = lane & 15, l4 = lane >> 4;
    const int brow0 = b * Sc + r0;

    // ---- phase 0: zero Sl; stage bf1/Wf2 (0-padded); fw
    {
        bf16x8 z = {};
        for (int t = tid; t < SROWS * SLD / 8; t += 256) ((bf16x8*)Sl)[t] = z;
    }
    for (int t = tid; t < 224; t += 256) {
        bf1l[t] = (t < Sc) ? bf1[t] : 0.f;
        wf2l[t] = (t < Sc) ? Wf2[t] : 0.f;
    }
    if (tid < CH) fwl[tid] = fw[tid];

    // ---- preload Q A-fragments from global (registers)
    bf16x8 af[NG][QT][2];
    #pragma unroll
    for (int g = 0; g < NG; ++g) {
        #pragma unroll
        for (int t = 0; t < QT; ++t) {
            int sr = t * 16 + l15;
            int kk = (sr < GR) ? (sr >> 3) : 0;
            int rr = (sr < GR) ? (sr & 7) : 0;
            const short* qp = proj_bf + ((size_t)QP[g * CPG + kk] * NPc + brow0 + rr) * Dc + h * HDc;
            #pragma unroll
            for (int ks = 0; ks < 2; ++ks)
                af[g][t][ks] = *(const bf16x8*)(qp + ks * 32 + l4 * 8);
        }
    }
    __syncthreads();

    // ---- scores: S[m][j] = fw[c] * (q_m . k_j)  (MFMA, bf16 out to Sl)
    for (int nt = wv; nt < 13; nt += 4) {
        int j = nt * 16 + l15;
        bf16x8 bfr[NG][2];
        #pragma unroll
        for (int g = 0; g < NG; ++g) {
            const short* Kb = proj_bf + ((size_t)KP[g] * NPc + (size_t)b * Sc) * Dc + h * HDc;
            #pragma unroll
            for (int ks = 0; ks < 2; ++ks)
                bfr[g][ks] = *(const bf16x8*)(Kb + (size_t)j * Dc + ks * 32 + l4 * 8);
        }
        #pragma unroll
        for (int g = 0; g < NG; ++g) {
            #pragma unroll
            for (int t = 0; t < QT; ++t) {
                f32x4 c = {};
                c = mfma16(af[g][t][0], bfr[g][0], c);
                c = mfma16(af[g][t][1], bfr[g][1], c);
                int k = t * 2 + (l4 >> 1);
                if (j < Sc && k < CPG) {
                    float f = fwl[CG[g * CPG + k]];
                    int srb = t * 16 + l4 * 4;
                    #pragma unroll
                    for (int i = 0; i < 4; ++i)
                        Sl[(g * GR + srb + i) * SLD + j] = f2bf(c[i] * f);
                }
            }
        }
    }
    __syncthreads();

    // ---- gate (swapped): C[j][m] = sum_i WT[j][i] * S[m][i]; e[m] reduce
    {
        float epart[MT2];
        #pragma unroll
        for (int mt = 0; mt < MT2; ++mt) epart[mt] = 0.f;

        for (int nt = wv; nt < 13; nt += 4) {
            int jr = nt * 16 + l15;
            float4 b1 = *(const float4*)(bf1l + nt * 16 + l4 * 4);
            float4 w2 = *(const float4*)(wf2l + nt * 16 + l4 * 4);
            f32x4 cg[MT2];
            #pragma unroll
            for (int mt = 0; mt < MT2; ++mt) cg[mt] = (f32x4){};
            #pragma unroll
            for (int ks = 0; ks < 7; ++ks) {
                bf16x8 aa = *(const bf16x8*)(WT + (size_t)jr * 224 + ks * 32 + l4 * 8);
                #pragma unroll
                for (int mt = 0; mt < MT2; ++mt) {
                    bf16x8 bb = *(const bf16x8*)(Sl + (mt * 16 + l15) * SLD + ks * 32 + l4 * 8);
                    cg[mt] = mfma16(aa, bb, cg[mt]);
                }
            }
            #pragma unroll
            for (int mt = 0; mt < MT2; ++mt) {
                float s = fmaxf(cg[mt][0] + b1.x, 0.f) * w2.x
                        + fmaxf(cg[mt][1] + b1.y, 0.f) * w2.y
                        + fmaxf(cg[mt][2] + b1.z, 0.f) * w2.z
                        + fmaxf(cg[mt][3] + b1.w, 0.f) * w2.w;
                s += __shfl_xor(s, 16, 64);
                s += __shfl_xor(s, 32, 64);
                epart[mt] += s;
            }
        }
        if (l4 == 0) {
            #pragma unroll
            for (int mt = 0; mt < MT2; ++mt)
                evw[wv * SROWS + mt * 16 + l15] = epart[mt];
        }
    }
    __syncthreads();

    // ---- channel softmax per row
    if (tid < R) {
        int r = tid;
        float e[CH]; float mx = -1e30f;
        #pragma unroll
        for (int c = 0; c < CH; ++c) {
            int m = M2S[c] + r;
            float s = evw[0 * SROWS + m] + evw[1 * SROWS + m]
                    + evw[2 * SROWS + m] + evw[3 * SROWS + m];
            e[c] = s; mx = fmaxf(mx, s);
        }
        float sum = 0.f;
        #pragma unroll
        for (int c = 0; c < CH; ++c) { e[c] = __expf(e[c] - mx); sum += e[c]; }
        float inv = 1.f / sum;
        #pragma unroll
        for (int c = 0; c < CH; ++c) wch[M2S[c] + r] = e[c] * inv;
    }
    __syncthreads();

    // ---- gated sum + scale + mask -> gbuf (fp32)
    if (tid < Sc) {
        int j = tid;
        const float* mrow = mask + ((size_t)b * Sc + r0) * Sc + j;
        #pragma unroll
        for (int r = 0; r < R; ++r) {
            float acc = 0.f;
            #pragma unroll
            for (int c = 0; c < CH; ++c) {
                int m = M2S[c] + r;
                acc += wch[m] * bf2f(Sl[m * SLD + j]);
            }
            gbuf[r * 200 + j] = acc * SCALE + mrow[(size_t)r * Sc];
        }
    }
    __syncthreads();

    // ---- row softmax: wave wv owns rows wv and wv+4
    #pragma unroll
    for (int rr = 0; rr < 2; ++rr) {
        const int r = wv + rr * 4;
        float vals[4]; float mpart = -1e30f;
        #pragma unroll
        for (int t4 = 0; t4 < 4; ++t4) {
            int j = t4 * 64 + lane;
            vals[t4] = (j < Sc) ? gbuf[r * 200 + j] : -1e30f;
            mpart = fmaxf(mpart, vals[t4]);
        }
        #pragma unroll
        for (int off = 32; off >= 1; off >>= 1) mpart = fmaxf(mpart, __shfl_xor(mpart, off, 64));
        float spart = 0.f;
        #pragma unroll
        for (int t4 = 0; t4 < 4; ++t4) {
            int j = t4 * 64 + lane;
            if (j < Sc) {
                float exv = __expf(vals[t4] - mpart);
                gbuf[r * 200 + j] = exv;
                spart += exv;
            }
        }
        #pragma unroll
        for (int off = 32; off >= 1; off >>= 1) spart += __shfl_xor(spart, off, 64);
        float inv = 1.f / spart;
        #pragma unroll
        for (int t4 = 0; t4 < 4; ++t4) {
            int j = t4 * 64 + lane;
            if (j < Sc) gbuf[r * 200 + j] *= inv;
        }
    }
    // wave-local from here (each wave reads only its own rows)

    // ---- PV: rows wv, wv+4 share each V load
    {
        const float* vb = vf32 + ((size_t)b * Sc) * Dc + h * HDc + lane;
        const float* pA = gbuf + wv * 200;
        const float* pB = gbuf + (wv + 4) * 200;
        float aA0 = 0.f, aA1 = 0.f, aA2 = 0.f, aA3 = 0.f;
        float aB0 = 0.f, aB1 = 0.f, aB2 = 0.f, aB3 = 0.f;
        for (int j = 0; j < Sc; j += 4) {
            float v0 = vb[(size_t)(j + 0) * Dc];
            float v1 = vb[(size_t)(j + 1) * Dc];
            float v2 = vb[(size_t)(j + 2) * Dc];
            float v3 = vb[(size_t)(j + 3) * Dc];
            aA0 += pA[j] * v0; aA1 += pA[j + 1] * v1; aA2 += pA[j + 2] * v2; aA3 += pA[j + 3] * v3;
            aB0 += pB[j] * v0; aB1 += pB[j + 1] * v1; aB2 += pB[j + 2] * v2; aB3 += pB[j + 3] * v3;
        }
        ctx_out[((size_t)(brow0 + wv)) * Dc + h * HDc + lane]     = aA0 + aA1 + aA2 + aA3;
        ctx_out[((size_t)(brow0 + wv + 4)) * Dc + h * HDc + lane] = aB0 + aB1 + aB2 + aB3;
    }
}

// ---------------------------------------------------------------------------
// Kernel 2 (v4): merged 9-channel + 4-channel fused attention
// grid = 6400 + 6400 blocks of 256 threads
// ---------------------------------------------------------------------------
__global__ __launch_bounds__(256, 3) void fused4(
    const short* __restrict__ proj_bf,
    const float* __restrict__ viv,
    const float* __restrict__ vhav,
    const float* __restrict__ fw9,
    const float* __restrict__ fw4,
    const float* __restrict__ mask,
    const short* __restrict__ WT,
    const float* __restrict__ bf1,
    const float* __restrict__ Wf2,
    float* __restrict__ ctx,
    float* __restrict__ ctxc)
{
    __shared__ __align__(16) short Sl[80 * 232];
    __shared__ float gbuf[8 * 200];
    __shared__ float evw[4 * 80];
    __shared__ float wch[80];
    __shared__ float fwl[9];
    __shared__ float bf1l[224];
    __shared__ float wf2l[224];

    const int bid = blockIdx.x;
    if (bid < 6400) {
        fused_body<9, 3, 3, 2, 5>(bid, proj_bf, viv, fw9, mask, WT, bf1, Wf2, ctx,
                                  c_KP9, c_QP9, c_CG9, c_M2S9,
                                  Sl, gbuf, evw, wch, fwl, bf1l, wf2l);
    } else {
        fused_body<4, 2, 2, 1, 2>(bid - 6400, proj_bf, vhav, fw4, mask, WT, bf1, Wf2, ctxc,
                                  c_KP4, c_QP4, c_CG4, c_M2S4,
                                  Sl, gbuf, evw, wch, fwl, bf1l, wf2l);
    }
}

// ---------------------------------------------------------------------------
// Kernel 3: out = LayerNorm( A @ W + bias + resid ) * gamma + beta
// ---------------------------------------------------------------------------
__global__ __launch_bounds__(256) void out_ln_kernel(
    const float* __restrict__ Actx,
    const float* __restrict__ W,
    const float* __restrict__ bias,
    const float* __restrict__ resid,
    const float* __restrict__ gamma,
    const float* __restrict__ beta,
    float* __restrict__ out)
{
    const int m0 = blockIdx.x * 16;
    const int tid = threadIdx.x;

    __shared__ float As[16][256];
    __shared__ float ylds[16][256];

    for (int t = tid; t < 16 * 64; t += 256) {
        int r = t >> 6, k4 = t & 63;
        ((float4*)As[r])[k4] = ((const float4*)(Actx + (size_t)(m0 + r) * Dc))[k4];
    }
    __syncthreads();

    float acc[16];
    #pragma unroll
    for (int r = 0; r < 16; r++) acc[r] = 0.f;

    for (int k = 0; k < 256; k += 4) {
        float w0 = W[(size_t)(k    ) * Dc + tid];
        float w1 = W[(size_t)(k + 1) * Dc + tid];
        float w2 = W[(size_t)(k + 2) * Dc + tid];
        float w3 = W[(size_t)(k + 3) * Dc + tid];
        #pragma unroll
        for (int r = 0; r < 16; r++) {
            float4 a4 = ((float4*)As[r])[k >> 2];
            acc[r] += a4.x * w0 + a4.y * w1 + a4.z * w2 + a4.w * w3;
        }
    }

    const float bv = bias[tid];
    #pragma unroll
    for (int r = 0; r < 16; r++) {
        ylds[r][tid] = acc[r] + bv + resid[(size_t)(m0 + r) * Dc + tid];
    }
    __syncthreads();

    const int lane = tid & 63;
    const int wv   = tid >> 6;
    for (int r = wv * 4; r < wv * 4 + 4; r++) {
        float v4[4];
        float s = 0.f, s2 = 0.f;
        #pragma unroll
        for (int t4 = 0; t4 < 4; t4++) {
            float v = ylds[r][t4 * 64 + lane];
            v4[t4] = v;
            s += v;
            s2 += v * v;
        }
        #pragma unroll
        for (int off = 32; off >= 1; off >>= 1) {
            s  += __shfl_xor(s, off, 64);
            s2 += __shfl_xor(s2, off, 64);
        }
        float m   = s * (1.f / 256.f);
        float var = s2 * (1.f / 256.f) - m * m;
        float rstd = rsqrtf(var + 1e-12f);
        #pragma unroll
        for (int t4 = 0; t4 < 4; t4++) {
            int ccol = t4 * 64 + lane;
            out[(size_t)(m0 + r) * Dc + ccol] = (v4[t4] - m) * rstd * gamma[ccol] + beta[ccol];
        }
    }
}

// ---------------------------------------------------------------------------
// Launcher
// ---------------------------------------------------------------------------
extern "C" void kernel_launch(void* const* d_in, const int* in_sizes, int n_in,
                              void* d_out, int out_size, void* d_ws, size_t ws_size,
                              hipStream_t stream) {
    const float* X    = (const float*)d_in[0];
    const float* AT   = (const float*)d_in[1];
    const float* P    = (const float*)d_in[2];
    const float* HA   = (const float*)d_in[3];
    const float* mask = (const float*)d_in[4];
    const float* fw   = (const float*)d_in[5];
    const float* fwc  = (const float*)d_in[6];

    const float* Wq   = (const float*)d_in[7];
    const float* bq   = (const float*)d_in[8];
    const float* Wk   = (const float*)d_in[9];
    const float* bk   = (const float*)d_in[10];
    const float* Wv   = (const float*)d_in[11];
    const float* bv   = (const float*)d_in[12];
    const float* Wqp  = (const float*)d_in[13];
    const float* bqp  = (const float*)d_in[14];
    const float* Wkp  = (const float*)d_in[15];
    const float* bkp  = (const float*)d_in[16];
    const float* Waq  = (const float*)d_in[17];
    const float* baq  = (const float*)d_in[18];
    const float* Wak  = (const float*)d_in[19];
    const float* bak  = (const float*)d_in[20];
    const float* Wav  = (const float*)d_in[21];
    const float* bav  = (const float*)d_in[22];
    const float* Wqic = (const float*)d_in[23];
    const float* bqic = (const float*)d_in[24];
    const float* Wqci = (const float*)d_in[25];
    const float* bqci = (const float*)d_in[26];
    const float* Wqpc = (const float*)d_in[27];
    const float* bqpc = (const float*)d_in[28];
    const float* Wqcp = (const float*)d_in[29];
    const float* bqcp = (const float*)d_in[30];
    const float* Wf1  = (const float*)d_in[31];
    const float* bf1  = (const float*)d_in[32];
    const float* Wf2  = (const float*)d_in[33];
    const float* bf2  = (const float*)d_in[34];
    const float* Wd   = (const float*)d_in[35];
    const float* bd   = (const float*)d_in[36];
    const float* ln_g = (const float*)d_in[37];
    const float* ln_b = (const float*)d_in[38];
    const float* Wda  = (const float*)d_in[39];
    const float* bda  = (const float*)d_in[40];
    const float* lna_g= (const float*)d_in[41];
    const float* lna_b= (const float*)d_in[42];

    char* w = (char*)d_ws;
    short* proj_bf = (short*)w;  w += (size_t)NPROJ * NPc * Dc * sizeof(short);
    short* WT      = (short*)w;  w += (size_t)224 * 224 * sizeof(short);
    float* viv     = (float*)w;  w += (size_t)NPc * Dc * sizeof(float);
    float* vhav    = (float*)w;  w += (size_t)NPc * Dc * sizeof(float);
    float* ctx     = (float*)w;  w += (size_t)NPc * Dc * sizeof(float);
    float* ctxc    = (float*)w;  w += (size_t)NPc * Dc * sizeof(float);

    ProjArgs pa;
    const float* Amat[NPROJ] = {X, X, X, P, P, AT, AT, HA, HA, HA, X, AT, AT, HA, P};
    const float* Wmat[NPROJ] = {Wq, Wk, Wv, Wqp, Wkp, Waq, Wak, Waq, Wak, Wav, Wqic, Wqci, Wqcp, Wqcp, Wqpc};
    const float* bmat[NPROJ] = {bq, bk, bv, bqp, bkp, baq, bak, baq, bak, bav, bqic, bqci, bqcp, bqcp, bqpc};
    for (int i = 0; i < NPROJ; i++) {
        pa.A[i] = Amat[i]; pa.W[i] = Wmat[i]; pa.bias[i] = bmat[i];
        pa.outf[i] = nullptr;
    }
    pa.outf[2] = viv;    // iv
    pa.outf[9] = vhav;   // hav

    // 1. projections (bf16 + fp32 for V)
    proj_kernel<<<dim3(NPc / 32, NPROJ), 256, 0, stream>>>(pa, proj_bf);

    // 1b. Wf1^T bf16 (zero-padded to 224x224)
    wf1t_kernel<<<(224 * 224 + 255) / 256, 256, 0, stream>>>(Wf1, WT);

    // 2. merged fused attention (9ch blocks 0..6399, 4ch blocks 6400..12799)
    fused4<<<12800, 256, 0, stream>>>(proj_bf, viv, vhav, fw, fwc, mask, WT, bf1, Wf2, ctx, ctxc);

    // 3. output projections + residual + LayerNorm
    float* out0 = (float*)d_out;
    float* out1 = out0 + (size_t)NPc * Dc;
    out_ln_kernel<<<NPc / 16, 256, 0, stream>>>(ctx,  Wd,  bd,  X,  ln_g,  ln_b,  out0);
    out_ln_kernel<<<NPc / 16, 256, 0, stream>>>(ctxc, Wda, bda, HA, lna_g, lna_b, out1);
}